// Round 14
// baseline (575.430 us; speedup 1.0000x reference)
//
#include <hip/hip_runtime.h>

namespace {

constexpr int NN  = 50000;
constexpr int EE  = 1000000;
constexpr int EE2 = EE + NN;          // edges + self loops
constexpr int ND  = 64;               // node_dim
constexpr int F1  = 128;              // 4 heads * 32
constexpr int F2  = 32;               // hidden
constexpr float NEG = 0.2f;

typedef unsigned short ushort_t;
typedef _Float16 half_t;
typedef _Float16 half2_t __attribute__((ext_vector_type(2)));

__device__ __forceinline__ unsigned short f2h(float f) {
  union { half_t h; unsigned short u; } c; c.h = (half_t)f; return c.u;
}
__device__ __forceinline__ float h2f(unsigned short v) {
  union { unsigned short u; half_t h; } c; c.u = v; return (float)c.h;
}
__device__ __forceinline__ half2_t u2h2(unsigned u) {
  union { unsigned u; half2_t h; } c; c.u = u; return c.h;
}
__device__ __forceinline__ unsigned pack2(float x, float y) {
  return (unsigned)f2h(x) | ((unsigned)f2h(y) << 16);
}
__device__ __forceinline__ half2_t mkh2(float x, float y) {
  half2_t r; r.x = (half_t)x; r.y = (half_t)y; return r;
}

#if __has_builtin(__builtin_amdgcn_fdot2)
#define FDOT2(a, b, c) __builtin_amdgcn_fdot2((a), (b), (c), false)
#else
#define FDOT2(a, b, c) ((float)(a).x * (float)(b).x + (float)(a).y * (float)(b).y + (c))
#endif

__global__ __launch_bounds__(256) void k_deg(const int* __restrict__ ei,
                                             int* __restrict__ deg) {
  int e = blockIdx.x * 256 + threadIdx.x;
  if (e < EE) atomicAdd(&deg[ei[EE + e]], 1);
}

// single block: each thread owns 49 contiguous nodes; block-scan of 1024 partials.
__global__ __launch_bounds__(1024) void k_scan(const int* __restrict__ deg,
                                               int* __restrict__ rowstart) {
  __shared__ int sh[1024];
  int t = threadIdx.x;
  int base = t * 49;
  int end = base + 49; if (end > NN) end = NN;
  int s = 0;
  for (int i = base; i < end; ++i) s += deg[i] + 1;
  sh[t] = s;
  __syncthreads();
  for (int off = 1; off < 1024; off <<= 1) {
    int v = (t >= off) ? sh[t - off] : 0;
    __syncthreads();
    sh[t] += v;
    __syncthreads();
  }
  int run = (t == 0) ? 0 : sh[t - 1];
  for (int i = base; i < end; ++i) { rowstart[i] = run; run += deg[i] + 1; }
  if (t == 1023) rowstart[NN] = sh[1023];
}

// CSR fill: esd (src,dst), f16-permuted edge_attr (eperm), self-loop slot per node.
__global__ __launch_bounds__(256) void k_fill(const int* __restrict__ ei,
                                              const float* __restrict__ edge_attr,
                                              const int* __restrict__ rowstart,
                                              int* __restrict__ cursor,
                                              int2* __restrict__ esd,
                                              ushort_t* __restrict__ eperm,
                                              int* __restrict__ loopos) {
  int i = blockIdx.x * 256 + threadIdx.x;
  if (i >= EE2) return;
  int sn, d;
  if (i < EE) { sn = ei[i]; d = ei[EE + i]; }
  else        { sn = i - EE; d = sn; }
  int pos = rowstart[d] + atomicAdd(&cursor[d], 1);
  esd[pos] = make_int2(sn, d);
  if (i < EE) {
    const float4* s4 = (const float4*)(edge_attr + (size_t)i * 16);
    float4 a = s4[0], b = s4[1], c = s4[2], e = s4[3];
    uint4 lo, hi;
    lo.x = pack2(a.x, a.y); lo.y = pack2(a.z, a.w);
    lo.z = pack2(b.x, b.y); lo.w = pack2(b.z, b.w);
    hi.x = pack2(c.x, c.y); hi.y = pack2(c.z, c.w);
    hi.z = pack2(e.x, e.y); hi.w = pack2(e.z, e.w);
    uint4* t4 = (uint4*)(eperm + (size_t)pos * 16);
    t4[0] = lo; t4[1] = hi;
  } else {
    loopos[d] = pos;
  }
}

// mean of incoming edge attrs -> written into eperm at the self-loop slot (f16).
__global__ __launch_bounds__(256) void k_loopattr(const int* __restrict__ rowstart,
                                                  const int* __restrict__ loopos,
                                                  ushort_t* __restrict__ eperm) {
  int tid = blockIdx.x * 256 + threadIdx.x;
  if (tid >= NN * 16) return;
  int n = tid >> 4, k = tid & 15;
  int s = rowstart[n], t = rowstart[n + 1];
  int lp = loopos[n];
  float acc = 0.f;
  for (int i = s; i < t; ++i) {
    if (i != lp) acc += h2f(eperm[(size_t)i * 16 + k]);
  }
  float dg = (float)(t - s - 1);
  eperm[(size_t)lp * 16 + k] = f2h(acc / fmaxf(dg, 1.f));
}

// pack x rows into f16 k-pairs
__global__ __launch_bounds__(256) void k_xprep(const float* __restrict__ x,
                                               unsigned* __restrict__ xh) {
  int tid = blockIdx.x * 256 + threadIdx.x;
  if (tid >= NN * 32) return;
  float2 v = ((const float2*)x)[tid];
  xh[tid] = pack2(v.x, v.y);
}

// pack weights into f16 k-pairs: Wp[kp*F + j] = (W[2kp][j], W[2kp+1][j])
__global__ __launch_bounds__(256) void k_wprep(const float* __restrict__ W1l,
                                               const float* __restrict__ W1r,
                                               const float* __restrict__ W2l,
                                               const float* __restrict__ W2r,
                                               unsigned* __restrict__ W1lp,
                                               unsigned* __restrict__ W1rp,
                                               unsigned* __restrict__ W2lp,
                                               unsigned* __restrict__ W2rp) {
  int tid = blockIdx.x * 256 + threadIdx.x;
  if (tid < 32 * 128) {
    int kp = tid >> 7, j = tid & 127;
    W1lp[tid] = pack2(W1l[(2 * kp) * F1 + j], W1l[(2 * kp + 1) * F1 + j]);
    W1rp[tid] = pack2(W1r[(2 * kp) * F1 + j], W1r[(2 * kp + 1) * F1 + j]);
  }
  if (tid < 64 * 32) {
    int kp = tid >> 5, c = tid & 31;
    W2lp[tid] = pack2(W2l[(2 * kp) * F2 + c], W2l[(2 * kp + 1) * F2 + c]);
    W2rp[tid] = pack2(W2r[(2 * kp) * F2 + c], W2r[(2 * kp + 1) * F2 + c]);
  }
}

// xform1: thread = (node, 4-output group); fdot2, coalesced uint4 W loads.
__global__ __launch_bounds__(256) void k_xform1(const unsigned* __restrict__ xh,
                                                const unsigned* __restrict__ W1lp,
                                                const unsigned* __restrict__ W1rp,
                                                const float* __restrict__ b1l,
                                                const float* __restrict__ b1r,
                                                ushort_t* __restrict__ xlh,
                                                ushort_t* __restrict__ xrh) {
  int tid = blockIdx.x * 256 + threadIdx.x;
  if (tid >= NN * 32) return;
  int n = tid >> 5, g = tid & 31;
  float4 bl = *(const float4*)(b1l + 4 * g);
  float4 br = *(const float4*)(b1r + 4 * g);
  float al0 = bl.x, al1 = bl.y, al2 = bl.z, al3 = bl.w;
  float ar0 = br.x, ar1 = br.y, ar2 = br.z, ar3 = br.w;
  const uint4* xp = (const uint4*)(xh + (size_t)n * 32);
  const uint4* wl = (const uint4*)W1lp;
  const uint4* wr = (const uint4*)W1rp;
#pragma unroll
  for (int kq = 0; kq < 8; ++kq) {
    uint4 xq = xp[kq];
    unsigned xs[4] = {xq.x, xq.y, xq.z, xq.w};
#pragma unroll
    for (int i = 0; i < 4; ++i) {
      int kp = 4 * kq + i;
      uint4 a = wl[kp * 32 + g];
      uint4 b = wr[kp * 32 + g];
      half2_t xv = u2h2(xs[i]);
      al0 = FDOT2(xv, u2h2(a.x), al0);
      al1 = FDOT2(xv, u2h2(a.y), al1);
      al2 = FDOT2(xv, u2h2(a.z), al2);
      al3 = FDOT2(xv, u2h2(a.w), al3);
      ar0 = FDOT2(xv, u2h2(b.x), ar0);
      ar1 = FDOT2(xv, u2h2(b.y), ar1);
      ar2 = FDOT2(xv, u2h2(b.z), ar2);
      ar3 = FDOT2(xv, u2h2(b.w), ar3);
    }
  }
  uint2 ol, orr;
  ol.x = pack2(al0, al1); ol.y = pack2(al2, al3);
  orr.x = pack2(ar0, ar1); orr.y = pack2(ar2, ar3);
  *(uint2*)(xlh + (size_t)n * F1 + 4 * g) = ol;
  *(uint2*)(xrh + (size_t)n * F1 + 4 * g) = orr;
}

// FUSED layer-1 GAT: logits + exp + per-dst-run register accumulation,
// flush via fp32 atomics on dst change. Wave per contiguous CSR chunk.
__global__ __launch_bounds__(256, 4) void k_gat1(const ushort_t* __restrict__ eperm,
                                                 const int2* __restrict__ esd,
                                                 const ushort_t* __restrict__ xlh,
                                                 const ushort_t* __restrict__ xrh,
                                                 const float* __restrict__ W1e,
                                                 const float* __restrict__ att1,
                                                 float* __restrict__ h1num,
                                                 float* __restrict__ h1den) {
  int lane = threadIdx.x & 63;
  int h = lane >> 4, q = lane & 15, j = h * 32 + 2 * q;
  half2_t w0p[8], w1p[8];
#pragma unroll
  for (int k = 0; k < 8; ++k) {
    w0p[k] = mkh2(W1e[(2 * k) * F1 + j],     W1e[(2 * k + 1) * F1 + j]);
    w1p[k] = mkh2(W1e[(2 * k) * F1 + j + 1], W1e[(2 * k + 1) * F1 + j + 1]);
  }
  float a0 = att1[j], a1 = att1[j + 1];
  int nw  = (gridDim.x * 256) >> 6;
  int wid = __builtin_amdgcn_readfirstlane((blockIdx.x * 256 + threadIdx.x) >> 6);
  int C = (EE2 + nw - 1) / nw;
  int start = wid * C;
  if (start >= EE2) return;
  int end = min(start + C, EE2);
  const int last = EE2 - 1;

  int2 sdc = esd[start];
  int2 sd1 = esd[min(start + 1, last)];
  const uint4* ep0 = (const uint4*)(eperm + (size_t)start * 16);
  uint4 ca = ep0[0], cb = ep0[1];
  unsigned ul = *(const unsigned*)(xlh + (size_t)sdc.x * F1 + j);
  unsigned ur = *(const unsigned*)(xrh + (size_t)sdc.y * F1 + j);

  int cur = sdc.y;
  float num0 = 0.f, num1 = 0.f, den = 0.f;

  for (int pos = start; pos < end; ++pos) {
    // prefetch next edge
    int2 sd2 = esd[min(pos + 2, last)];
    const uint4* epn = (const uint4*)(eperm + (size_t)min(pos + 1, last) * 16);
    uint4 na = epn[0], nb = epn[1];
    unsigned uln = *(const unsigned*)(xlh + (size_t)sd1.x * F1 + j);
    unsigned urn = (sd1.y != sdc.y) ? *(const unsigned*)(xrh + (size_t)sd1.y * F1 + j)
                                    : ur;
    // compute current logit (16 fdot2)
    half2_t e2[8];
    e2[0] = u2h2(ca.x); e2[1] = u2h2(ca.y); e2[2] = u2h2(ca.z); e2[3] = u2h2(ca.w);
    e2[4] = u2h2(cb.x); e2[5] = u2h2(cb.y); e2[6] = u2h2(cb.z); e2[7] = u2h2(cb.w);
    float ea0 = 0.f, ea1 = 0.f;
#pragma unroll
    for (int k = 0; k < 8; ++k) {
      ea0 = FDOT2(e2[k], w0p[k], ea0);
      ea1 = FDOT2(e2[k], w1p[k], ea1);
    }
    half2_t ul2 = u2h2(ul), ur2 = u2h2(ur);
    float m0 = (float)ul2.x + (float)ur2.x + ea0;
    float m1 = (float)ul2.y + (float)ur2.y + ea1;
    m0 = fmaxf(m0, NEG * m0);
    m1 = fmaxf(m1, NEG * m1);
    float p = a0 * m0 + a1 * m1;
#pragma unroll
    for (int m = 8; m >= 1; m >>= 1) p += __shfl_xor(p, m);
    float pe = __expf(p);
    // flush-on-dst-change (wave-uniform branch), then accumulate
    if (sdc.y != cur) {
      atomicAdd(&h1num[(size_t)cur * F1 + j], num0);
      atomicAdd(&h1num[(size_t)cur * F1 + j + 1], num1);
      if (q == 0) atomicAdd(&h1den[cur * 4 + h], den);
      num0 = 0.f; num1 = 0.f; den = 0.f;
      cur = sdc.y;
    }
    num0 += pe * (float)ul2.x;
    num1 += pe * (float)ul2.y;
    den  += pe;
    // rotate
    sdc = sd1; sd1 = sd2; ca = na; cb = nb; ul = uln; ur = urn;
  }
  atomicAdd(&h1num[(size_t)cur * F1 + j], num0);
  atomicAdd(&h1num[(size_t)cur * F1 + j + 1], num1);
  if (q == 0) atomicAdd(&h1den[cur * 4 + h], den);
}

// finish layer 1: h1 = ELU(num/den + bias) -> packed f16 pairs
__global__ __launch_bounds__(256) void k_gatfin1(const float* __restrict__ h1num,
                                                 const float* __restrict__ h1den,
                                                 const float* __restrict__ bias1,
                                                 unsigned* __restrict__ h1h) {
  int tid = blockIdx.x * 256 + threadIdx.x;
  if (tid >= NN * 64) return;
  int n = tid >> 6, lane = tid & 63;
  float2 nm = *(const float2*)(h1num + (size_t)n * F1 + 2 * lane);
  float den = h1den[n * 4 + (lane >> 4)];
  float2 bs = *(const float2*)(bias1 + 2 * lane);
  float o0 = nm.x / den + bs.x;
  float o1 = nm.y / den + bs.y;
  o0 = o0 > 0.f ? o0 : (__expf(o0) - 1.f);   // ELU
  o1 = o1 > 0.f ? o1 : (__expf(o1) - 1.f);
  h1h[tid] = pack2(o0, o1);
}

// xform2: thread = (node, 4-output group of 8); fdot2 on packed pairs.
__global__ __launch_bounds__(256) void k_xform2(const unsigned* __restrict__ h1h,
                                                const unsigned* __restrict__ W2lp,
                                                const unsigned* __restrict__ W2rp,
                                                const float* __restrict__ b2l,
                                                const float* __restrict__ b2r,
                                                ushort_t* __restrict__ xl2h,
                                                ushort_t* __restrict__ xr2h) {
  int tid = blockIdx.x * 256 + threadIdx.x;
  if (tid >= NN * 8) return;
  int n = tid >> 3, g = tid & 7;
  float4 bl = *(const float4*)(b2l + 4 * g);
  float4 br = *(const float4*)(b2r + 4 * g);
  float al0 = bl.x, al1 = bl.y, al2 = bl.z, al3 = bl.w;
  float ar0 = br.x, ar1 = br.y, ar2 = br.z, ar3 = br.w;
  const uint4* hp = (const uint4*)(h1h + (size_t)n * 64);
  const uint4* wl = (const uint4*)W2lp;
  const uint4* wr = (const uint4*)W2rp;
#pragma unroll 4
  for (int kq = 0; kq < 16; ++kq) {
    uint4 hq = hp[kq];
    unsigned hs[4] = {hq.x, hq.y, hq.z, hq.w};
#pragma unroll
    for (int i = 0; i < 4; ++i) {
      int kp = 4 * kq + i;
      uint4 a = wl[kp * 8 + g];
      uint4 b = wr[kp * 8 + g];
      half2_t hv = u2h2(hs[i]);
      al0 = FDOT2(hv, u2h2(a.x), al0);
      al1 = FDOT2(hv, u2h2(a.y), al1);
      al2 = FDOT2(hv, u2h2(a.z), al2);
      al3 = FDOT2(hv, u2h2(a.w), al3);
      ar0 = FDOT2(hv, u2h2(b.x), ar0);
      ar1 = FDOT2(hv, u2h2(b.y), ar1);
      ar2 = FDOT2(hv, u2h2(b.z), ar2);
      ar3 = FDOT2(hv, u2h2(b.w), ar3);
    }
  }
  uint2 ol, orr;
  ol.x = pack2(al0, al1); ol.y = pack2(al2, al3);
  orr.x = pack2(ar0, ar1); orr.y = pack2(ar2, ar3);
  *(uint2*)(xl2h + (size_t)n * F2 + 4 * g) = ol;
  *(uint2*)(xr2h + (size_t)n * F2 + 4 * g) = orr;
}

// FUSED layer-2 GAT: 16-lane group per contiguous sub-chunk; register
// accumulation with flush-on-dst-change atomics. No conditional gathers
// (divergence removal: always load next ur).
__global__ __launch_bounds__(256, 4) void k_gat2(const ushort_t* __restrict__ eperm,
                                                 const int2* __restrict__ esd,
                                                 const ushort_t* __restrict__ xl2h,
                                                 const ushort_t* __restrict__ xr2h,
                                                 const float* __restrict__ W2e,
                                                 const float* __restrict__ att2,
                                                 float* __restrict__ h2num,
                                                 float* __restrict__ h2den) {
  int lane = threadIdx.x & 63;
  int g = lane >> 4, q = lane & 15, j = 2 * q;
  half2_t w0p[8], w1p[8];
#pragma unroll
  for (int k = 0; k < 8; ++k) {
    w0p[k] = mkh2(W2e[(2 * k) * F2 + j],     W2e[(2 * k + 1) * F2 + j]);
    w1p[k] = mkh2(W2e[(2 * k) * F2 + j + 1], W2e[(2 * k + 1) * F2 + j + 1]);
  }
  float a0 = att2[j], a1 = att2[j + 1];
  int nw  = (gridDim.x * 256) >> 6;
  int wid = (blockIdx.x * 256 + threadIdx.x) >> 6;
  int ngroups = nw * 4;
  int gid = wid * 4 + g;
  int C = (EE2 + ngroups - 1) / ngroups;
  int start = gid * C;
  if (start >= EE2) return;
  int end = min(start + C, EE2);
  const int last = EE2 - 1;

  int2 sdc = esd[start];
  int2 sd1 = esd[min(start + 1, last)];
  const uint4* ep0 = (const uint4*)(eperm + (size_t)start * 16);
  uint4 ca = ep0[0], cb = ep0[1];
  unsigned ul = *(const unsigned*)(xl2h + (size_t)sdc.x * F2 + j);
  unsigned ur = *(const unsigned*)(xr2h + (size_t)sdc.y * F2 + j);

  int cur = sdc.y;
  float num0 = 0.f, num1 = 0.f, den = 0.f;

  for (int pos = start; pos < end; ++pos) {
    int2 sd2 = esd[min(pos + 2, last)];
    const uint4* epn = (const uint4*)(eperm + (size_t)min(pos + 1, last) * 16);
    uint4 na = epn[0], nb = epn[1];
    unsigned uln = *(const unsigned*)(xl2h + (size_t)sd1.x * F2 + j);
    unsigned urn = *(const unsigned*)(xr2h + (size_t)sd1.y * F2 + j);
    half2_t e2[8];
    e2[0] = u2h2(ca.x); e2[1] = u2h2(ca.y); e2[2] = u2h2(ca.z); e2[3] = u2h2(ca.w);
    e2[4] = u2h2(cb.x); e2[5] = u2h2(cb.y); e2[6] = u2h2(cb.z); e2[7] = u2h2(cb.w);
    float ea = 0.f, eb = 0.f;
#pragma unroll
    for (int k = 0; k < 8; ++k) {
      ea = FDOT2(e2[k], w0p[k], ea);
      eb = FDOT2(e2[k], w1p[k], eb);
    }
    half2_t ul2 = u2h2(ul), ur2 = u2h2(ur);
    float m0 = (float)ul2.x + (float)ur2.x + ea;
    float m1 = (float)ul2.y + (float)ur2.y + eb;
    m0 = fmaxf(m0, NEG * m0);
    m1 = fmaxf(m1, NEG * m1);
    float p = a0 * m0 + a1 * m1;
#pragma unroll
    for (int m = 8; m >= 1; m >>= 1) p += __shfl_xor(p, m);
    float pe = __expf(p);
    if (sdc.y != cur) {
      atomicAdd(&h2num[(size_t)cur * F2 + j], num0);
      atomicAdd(&h2num[(size_t)cur * F2 + j + 1], num1);
      if (q == 0) atomicAdd(&h2den[cur], den);
      num0 = 0.f; num1 = 0.f; den = 0.f;
      cur = sdc.y;
    }
    num0 += pe * (float)ul2.x;
    num1 += pe * (float)ul2.y;
    den  += pe;
    sdc = sd1; sd1 = sd2; ca = na; cb = nb; ul = uln; ur = urn;
  }
  atomicAdd(&h2num[(size_t)cur * F2 + j], num0);
  atomicAdd(&h2num[(size_t)cur * F2 + j + 1], num1);
  if (q == 0) atomicAdd(&h2den[cur], den);
}

// finish layer 2: h2 = ELU(num/den + bias) (fp32 for classifier)
__global__ __launch_bounds__(256) void k_gatfin2(const float* __restrict__ h2num,
                                                 const float* __restrict__ h2den,
                                                 const float* __restrict__ bias2,
                                                 float* __restrict__ h2) {
  int tid = blockIdx.x * 256 + threadIdx.x;
  if (tid >= NN * 16) return;
  int n = tid >> 4, q = tid & 15;
  float2 nm = *(const float2*)(h2num + (size_t)n * F2 + 2 * q);
  float den = h2den[n];
  float2 bs = *(const float2*)(bias2 + 2 * q);
  float o0 = nm.x / den + bs.x;
  float o1 = nm.y / den + bs.y;
  o0 = o0 > 0.f ? o0 : (__expf(o0) - 1.f);   // ELU
  o1 = o1 > 0.f ? o1 : (__expf(o1) - 1.f);
  *(float2*)(h2 + (size_t)n * F2 + 2 * q) = make_float2(o0, o1);
}

// per-node halves of classifier layer 1
__global__ __launch_bounds__(256) void k_ucls(const float* __restrict__ h2,
                                              const float* __restrict__ Wc1,
                                              float* __restrict__ us,
                                              float* __restrict__ ud) {
  int tid = blockIdx.x * 256 + threadIdx.x;
  if (tid >= NN * F2) return;
  int n = tid >> 5, c = tid & 31;
  const float* hp = h2 + (size_t)n * F2;
  float a = 0.f, b = 0.f;
#pragma unroll 8
  for (int k = 0; k < 32; ++k) {
    float hv = hp[k];
    a += hv * Wc1[k * F2 + c];
    b += hv * Wc1[(32 + k) * F2 + c];
  }
  us[tid] = a;
  ud[tid] = b;
}

// classifier: contiguous 4-edge groups per wave, 2-deep pipeline (edge order).
__global__ __launch_bounds__(256, 4) void k_cls(const int* __restrict__ ei,
                                                const float* __restrict__ edge_attr,
                                                const float* __restrict__ us,
                                                const float* __restrict__ ud,
                                                const float* __restrict__ Wc1,
                                                const float* __restrict__ bc1,
                                                const float* __restrict__ Wc2,
                                                const float* __restrict__ bc2,
                                                float* __restrict__ out) {
  int lane = threadIdx.x & 63;
  int g = lane >> 4, q = lane & 15, j = 2 * q;
  float wk0[16], wk1[16];
#pragma unroll
  for (int k = 0; k < 16; ++k) {
    wk0[k] = Wc1[(64 + k) * F2 + j];
    wk1[k] = Wc1[(64 + k) * F2 + j + 1];
  }
  float b0 = bc1[j], b1 = bc1[j + 1], c0 = Wc2[j], c1 = Wc2[j + 1];
  float bb = bc2[0];
  int nw  = (gridDim.x * 256) >> 6;
  int wid = __builtin_amdgcn_readfirstlane((blockIdx.x * 256 + threadIdx.x) >> 6);
  int C = (((EE + nw - 1) / nw) + 3) & ~3;
  int start = wid * C;
  if (start >= EE) return;
  int end = min(start + C, EE);
  const int last = EE - 1;

  int e0c = min(start + g, last);
  int sn0 = ei[e0c], dn0 = ei[EE + e0c];
  int e1c = min(start + 4 + g, last);
  int sn1 = ei[e1c], dn1 = ei[EE + e1c];
  const float4* ep0 = (const float4*)(edge_attr + (size_t)e0c * 16);
  float4 ca0 = ep0[0], ca1 = ep0[1], ca2 = ep0[2], ca3 = ep0[3];
  float2 su = *(const float2*)(us + (size_t)sn0 * F2 + j);
  float2 du = *(const float2*)(ud + (size_t)dn0 * F2 + j);

  for (int base = start; base < end; base += 4) {
    int e2c = min(base + 8 + g, last);
    int sn2 = ei[e2c], dn2 = ei[EE + e2c];
    const float4* epn = (const float4*)(edge_attr + (size_t)min(base + 4 + g, last) * 16);
    float4 na0 = epn[0], na1 = epn[1], na2 = epn[2], na3 = epn[3];
    float2 sun = *(const float2*)(us + (size_t)sn1 * F2 + j);
    float2 dun = *(const float2*)(ud + (size_t)dn1 * F2 + j);
    float ev[16] = {ca0.x, ca0.y, ca0.z, ca0.w, ca1.x, ca1.y, ca1.z, ca1.w,
                    ca2.x, ca2.y, ca2.z, ca2.w, ca3.x, ca3.y, ca3.z, ca3.w};
    float acc0 = b0 + su.x + du.x;
    float acc1 = b1 + su.y + du.y;
#pragma unroll
    for (int k = 0; k < 16; ++k) { acc0 += ev[k] * wk0[k]; acc1 += ev[k] * wk1[k]; }
    float r = fmaxf(acc0, 0.f) * c0 + fmaxf(acc1, 0.f) * c1;
#pragma unroll
    for (int m = 8; m >= 1; m >>= 1) r += __shfl_xor(r, m);
    int e = base + g;
    if (q == 0 && e < end) out[e] = r + bb;
    sn1 = sn2; dn1 = dn2;
    ca0 = na0; ca1 = na1; ca2 = na2; ca3 = na3;
    su = sun; du = dun;
  }
}

}  // namespace

extern "C" void kernel_launch(void* const* d_in, const int* in_sizes, int n_in,
                              void* d_out, int out_size, void* d_ws, size_t ws_size,
                              hipStream_t stream) {
  const float* x         = (const float*)d_in[0];
  const int*   ei        = (const int*)d_in[1];
  const float* edge_attr = (const float*)d_in[2];
  const float* W1l  = (const float*)d_in[3];
  const float* b1l  = (const float*)d_in[4];
  const float* W1r  = (const float*)d_in[5];
  const float* b1r  = (const float*)d_in[6];
  const float* W1e  = (const float*)d_in[7];
  const float* att1 = (const float*)d_in[8];
  const float* bias1= (const float*)d_in[9];
  const float* W2l  = (const float*)d_in[10];
  const float* b2l  = (const float*)d_in[11];
  const float* W2r  = (const float*)d_in[12];
  const float* b2r  = (const float*)d_in[13];
  const float* W2e  = (const float*)d_in[14];
  const float* att2 = (const float*)d_in[15];
  const float* bias2= (const float*)d_in[16];
  const float* Wc1  = (const float*)d_in[17];
  const float* bc1  = (const float*)d_in[18];
  const float* Wc2  = (const float*)d_in[19];
  const float* bc2  = (const float*)d_in[20];
  float* out = (float*)d_out;

  // ---- workspace layout (4-byte words) ----
  int*  deg      = (int*)d_ws;                            // NN
  int*  cursor   = deg + NN;                              // NN
  int*  loopos   = cursor + NN;                           // NN
  int*  rowstart = loopos + NN;                           // 50008
  int2* esd      = (int2*)(rowstart + 50008);             // EE2 int2
  ushort_t* eperm = (ushort_t*)(esd + EE2);               // EE2*16 f16
  ushort_t* xlh  = eperm + (size_t)EE2 * 16;              // NN*128 f16
  ushort_t* xrh  = xlh + (size_t)NN * F1;                 // NN*128 f16
  float* h1num   = (float*)(xrh + (size_t)NN * F1);       // NN*128 f32
  float* h1den   = h1num + (size_t)NN * F1;               // NN*4
  unsigned* h1h  = (unsigned*)(h1den + (size_t)NN * 4);   // NN*64 u32
  unsigned* W1lp = h1h + (size_t)NN * 64;                 // 4096
  unsigned* W1rp = W1lp + 4096;                           // 4096
  unsigned* W2lp = W1rp + 4096;                           // 2048
  unsigned* W2rp = W2lp + 2048;                           // 2048
  unsigned* xh   = (unsigned*)h1num;                      // NN*32 (dead before h1num memset)
  // layer-2 overlays:
  ushort_t* xl2h = xlh;                                   // NN*32 f16
  ushort_t* xr2h = xl2h + (size_t)NN * F2;                // NN*32 f16
  float* h2num   = h1num;                                 // NN*32 f32 (h1num dead after gatfin1)
  float* h2den   = h1num + (size_t)NN * F2;               // NN
  float* h2      = h2den + NN;                            // NN*32
  float* us      = h2 + (size_t)NN * F2;                  // NN*32
  float* ud      = us + (size_t)NN * F2;                  // NN*32

  hipMemsetAsync(deg, 0, 2 * (size_t)NN * sizeof(int), stream);  // deg + cursor

  k_deg<<<(EE + 255) / 256, 256, 0, stream>>>(ei, deg);
  k_scan<<<1, 1024, 0, stream>>>(deg, rowstart);
  k_fill<<<(EE2 + 255) / 256, 256, 0, stream>>>(ei, edge_attr, rowstart, cursor,
                                                esd, eperm, loopos);
  k_loopattr<<<(NN * 16 + 255) / 256, 256, 0, stream>>>(rowstart, loopos, eperm);
  k_xprep<<<(NN * 32 + 255) / 256, 256, 0, stream>>>(x, xh);
  k_wprep<<<16, 256, 0, stream>>>(W1l, W1r, W2l, W2r, W1lp, W1rp, W2lp, W2rp);
  k_xform1<<<(NN * 32 + 255) / 256, 256, 0, stream>>>(xh, W1lp, W1rp, b1l, b1r, xlh, xrh);
  // zero layer-1 accumulators (after xform1: xh overlay is dead now)
  hipMemsetAsync(h1num, 0, (size_t)NN * 132 * sizeof(float), stream);
  k_gat1<<<4096, 256, 0, stream>>>(eperm, esd, xlh, xrh, W1e, att1, h1num, h1den);
  k_gatfin1<<<(NN * 64 + 255) / 256, 256, 0, stream>>>(h1num, h1den, bias1, h1h);
  k_xform2<<<(NN * 8 + 255) / 256, 256, 0, stream>>>(h1h, W2lp, W2rp, b2l, b2r, xl2h, xr2h);
  // zero layer-2 accumulators (h1num region dead after gatfin1)
  hipMemsetAsync(h2num, 0, (size_t)NN * 33 * sizeof(float), stream);
  k_gat2<<<4096, 256, 0, stream>>>(eperm, esd, xl2h, xr2h, W2e, att2, h2num, h2den);
  k_gatfin2<<<(NN * 16 + 255) / 256, 256, 0, stream>>>(h2num, h2den, bias2, h2);
  k_ucls<<<(NN * F2 + 255) / 256, 256, 0, stream>>>(h2, Wc1, us, ud);
  k_cls<<<4096, 256, 0, stream>>>(ei, edge_attr, us, ud, Wc1, bc1, Wc2, bc2, out);
}

// Round 15
// 562.968 us; speedup vs baseline: 1.0221x; 1.0221x over previous
//
#include <hip/hip_runtime.h>

namespace {

constexpr int NN  = 50000;
constexpr int EE  = 1000000;
constexpr int EE2 = EE + NN;          // edges + self loops
constexpr int ND  = 64;               // node_dim
constexpr int F1  = 128;              // 4 heads * 32
constexpr int F2  = 32;               // hidden
constexpr float NEG = 0.2f;

typedef unsigned short ushort_t;
typedef _Float16 half_t;
typedef _Float16 half2_t __attribute__((ext_vector_type(2)));

__device__ __forceinline__ unsigned short f2h(float f) {
  union { half_t h; unsigned short u; } c; c.h = (half_t)f; return c.u;
}
__device__ __forceinline__ float h2f(unsigned short v) {
  union { unsigned short u; half_t h; } c; c.u = v; return (float)c.h;
}
__device__ __forceinline__ half2_t u2h2(unsigned u) {
  union { unsigned u; half2_t h; } c; c.u = u; return c.h;
}
__device__ __forceinline__ unsigned pack2(float x, float y) {
  return (unsigned)f2h(x) | ((unsigned)f2h(y) << 16);
}
__device__ __forceinline__ half2_t mkh2(float x, float y) {
  half2_t r; r.x = (half_t)x; r.y = (half_t)y; return r;
}

#if __has_builtin(__builtin_amdgcn_fdot2)
#define FDOT2(a, b, c) __builtin_amdgcn_fdot2((a), (b), (c), false)
#else
#define FDOT2(a, b, c) ((float)(a).x * (float)(b).x + (float)(a).y * (float)(b).y + (c))
#endif

// FUSED prep: deg atomics + x f16-pack + weight f16-packs (all independent).
__global__ __launch_bounds__(256) void k_prep(const int* __restrict__ ei,
                                              int* __restrict__ deg,
                                              const float* __restrict__ x,
                                              unsigned* __restrict__ xh,
                                              const float* __restrict__ W1l,
                                              const float* __restrict__ W1r,
                                              const float* __restrict__ W2l,
                                              const float* __restrict__ W2r,
                                              unsigned* __restrict__ W1lp,
                                              unsigned* __restrict__ W1rp,
                                              unsigned* __restrict__ W2lp,
                                              unsigned* __restrict__ W2rp) {
  int tid = blockIdx.x * 256 + threadIdx.x;
  if (tid < EE) atomicAdd(&deg[ei[EE + tid]], 1);
  if (tid < NN * 32) {
    float2 v = ((const float2*)x)[tid];
    xh[tid] = pack2(v.x, v.y);
  }
  if (tid < 32 * 128) {
    int kp = tid >> 7, j = tid & 127;
    W1lp[tid] = pack2(W1l[(2 * kp) * F1 + j], W1l[(2 * kp + 1) * F1 + j]);
    W1rp[tid] = pack2(W1r[(2 * kp) * F1 + j], W1r[(2 * kp + 1) * F1 + j]);
  }
  if (tid < 64 * 32) {
    int kp = tid >> 5, c = tid & 31;
    W2lp[tid] = pack2(W2l[(2 * kp) * F2 + c], W2l[(2 * kp + 1) * F2 + c]);
    W2rp[tid] = pack2(W2r[(2 * kp) * F2 + c], W2r[(2 * kp + 1) * F2 + c]);
  }
}

// single block: each thread owns 49 contiguous nodes; block-scan of 1024 partials.
__global__ __launch_bounds__(1024) void k_scan(const int* __restrict__ deg,
                                               int* __restrict__ rowstart) {
  __shared__ int sh[1024];
  int t = threadIdx.x;
  int base = t * 49;
  int end = base + 49; if (end > NN) end = NN;
  int s = 0;
  for (int i = base; i < end; ++i) s += deg[i] + 1;
  sh[t] = s;
  __syncthreads();
  for (int off = 1; off < 1024; off <<= 1) {
    int v = (t >= off) ? sh[t - off] : 0;
    __syncthreads();
    sh[t] += v;
    __syncthreads();
  }
  int run = (t == 0) ? 0 : sh[t - 1];
  for (int i = base; i < end; ++i) { rowstart[i] = run; run += deg[i] + 1; }
  if (t == 1023) rowstart[NN] = sh[1023];
}

// CSR fill: esd (src,dst), f16-permuted edge_attr (eperm), self-loop slot per node.
__global__ __launch_bounds__(256) void k_fill(const int* __restrict__ ei,
                                              const float* __restrict__ edge_attr,
                                              const int* __restrict__ rowstart,
                                              int* __restrict__ cursor,
                                              int2* __restrict__ esd,
                                              ushort_t* __restrict__ eperm,
                                              int* __restrict__ loopos) {
  int i = blockIdx.x * 256 + threadIdx.x;
  if (i >= EE2) return;
  int sn, d;
  if (i < EE) { sn = ei[i]; d = ei[EE + i]; }
  else        { sn = i - EE; d = sn; }
  int pos = rowstart[d] + atomicAdd(&cursor[d], 1);
  esd[pos] = make_int2(sn, d);
  if (i < EE) {
    const float4* s4 = (const float4*)(edge_attr + (size_t)i * 16);
    float4 a = s4[0], b = s4[1], c = s4[2], e = s4[3];
    uint4 lo, hi;
    lo.x = pack2(a.x, a.y); lo.y = pack2(a.z, a.w);
    lo.z = pack2(b.x, b.y); lo.w = pack2(b.z, b.w);
    hi.x = pack2(c.x, c.y); hi.y = pack2(c.z, c.w);
    hi.z = pack2(e.x, e.y); hi.w = pack2(e.z, e.w);
    uint4* t4 = (uint4*)(eperm + (size_t)pos * 16);
    t4[0] = lo; t4[1] = hi;
  } else {
    loopos[d] = pos;
  }
}

// mean of incoming edge attrs -> written into eperm at the self-loop slot (f16).
__global__ __launch_bounds__(256) void k_loopattr(const int* __restrict__ rowstart,
                                                  const int* __restrict__ loopos,
                                                  ushort_t* __restrict__ eperm) {
  int tid = blockIdx.x * 256 + threadIdx.x;
  if (tid >= NN * 16) return;
  int n = tid >> 4, k = tid & 15;
  int s = rowstart[n], t = rowstart[n + 1];
  int lp = loopos[n];
  float acc = 0.f;
  for (int i = s; i < t; ++i) {
    if (i != lp) acc += h2f(eperm[(size_t)i * 16 + k]);
  }
  float dg = (float)(t - s - 1);
  eperm[(size_t)lp * 16 + k] = f2h(acc / fmaxf(dg, 1.f));
}

// xform1: thread = (node, 4-output group); fdot2, coalesced uint4 W loads.
__global__ __launch_bounds__(256) void k_xform1(const unsigned* __restrict__ xh,
                                                const unsigned* __restrict__ W1lp,
                                                const unsigned* __restrict__ W1rp,
                                                const float* __restrict__ b1l,
                                                const float* __restrict__ b1r,
                                                ushort_t* __restrict__ xlh,
                                                ushort_t* __restrict__ xrh) {
  int tid = blockIdx.x * 256 + threadIdx.x;
  if (tid >= NN * 32) return;
  int n = tid >> 5, g = tid & 31;
  float4 bl = *(const float4*)(b1l + 4 * g);
  float4 br = *(const float4*)(b1r + 4 * g);
  float al0 = bl.x, al1 = bl.y, al2 = bl.z, al3 = bl.w;
  float ar0 = br.x, ar1 = br.y, ar2 = br.z, ar3 = br.w;
  const uint4* xp = (const uint4*)(xh + (size_t)n * 32);
  const uint4* wl = (const uint4*)W1lp;
  const uint4* wr = (const uint4*)W1rp;
#pragma unroll
  for (int kq = 0; kq < 8; ++kq) {
    uint4 xq = xp[kq];
    unsigned xs[4] = {xq.x, xq.y, xq.z, xq.w};
#pragma unroll
    for (int i = 0; i < 4; ++i) {
      int kp = 4 * kq + i;
      uint4 a = wl[kp * 32 + g];
      uint4 b = wr[kp * 32 + g];
      half2_t xv = u2h2(xs[i]);
      al0 = FDOT2(xv, u2h2(a.x), al0);
      al1 = FDOT2(xv, u2h2(a.y), al1);
      al2 = FDOT2(xv, u2h2(a.z), al2);
      al3 = FDOT2(xv, u2h2(a.w), al3);
      ar0 = FDOT2(xv, u2h2(b.x), ar0);
      ar1 = FDOT2(xv, u2h2(b.y), ar1);
      ar2 = FDOT2(xv, u2h2(b.z), ar2);
      ar3 = FDOT2(xv, u2h2(b.w), ar3);
    }
  }
  uint2 ol, orr;
  ol.x = pack2(al0, al1); ol.y = pack2(al2, al3);
  orr.x = pack2(ar0, ar1); orr.y = pack2(ar2, ar3);
  *(uint2*)(xlh + (size_t)n * F1 + 4 * g) = ol;
  *(uint2*)(xrh + (size_t)n * F1 + 4 * g) = orr;
}

// FUSED layer-1 GAT: logits + exp + per-dst-run register accumulation,
// flush via fp32 atomics on dst change. Wave per contiguous CSR chunk.
__global__ __launch_bounds__(256, 4) void k_gat1(const ushort_t* __restrict__ eperm,
                                                 const int2* __restrict__ esd,
                                                 const ushort_t* __restrict__ xlh,
                                                 const ushort_t* __restrict__ xrh,
                                                 const float* __restrict__ W1e,
                                                 const float* __restrict__ att1,
                                                 float* __restrict__ h1num,
                                                 float* __restrict__ h1den) {
  int lane = threadIdx.x & 63;
  int h = lane >> 4, q = lane & 15, j = h * 32 + 2 * q;
  half2_t w0p[8], w1p[8];
#pragma unroll
  for (int k = 0; k < 8; ++k) {
    w0p[k] = mkh2(W1e[(2 * k) * F1 + j],     W1e[(2 * k + 1) * F1 + j]);
    w1p[k] = mkh2(W1e[(2 * k) * F1 + j + 1], W1e[(2 * k + 1) * F1 + j + 1]);
  }
  float a0 = att1[j], a1 = att1[j + 1];
  int nw  = (gridDim.x * 256) >> 6;
  int wid = __builtin_amdgcn_readfirstlane((blockIdx.x * 256 + threadIdx.x) >> 6);
  int C = (EE2 + nw - 1) / nw;
  int start = wid * C;
  if (start >= EE2) return;
  int end = min(start + C, EE2);
  const int last = EE2 - 1;

  int2 sdc = esd[start];
  int2 sd1 = esd[min(start + 1, last)];
  const uint4* ep0 = (const uint4*)(eperm + (size_t)start * 16);
  uint4 ca = ep0[0], cb = ep0[1];
  unsigned ul = *(const unsigned*)(xlh + (size_t)sdc.x * F1 + j);
  unsigned ur = *(const unsigned*)(xrh + (size_t)sdc.y * F1 + j);

  int cur = sdc.y;
  float num0 = 0.f, num1 = 0.f, den = 0.f;

  for (int pos = start; pos < end; ++pos) {
    // prefetch next edge
    int2 sd2 = esd[min(pos + 2, last)];
    const uint4* epn = (const uint4*)(eperm + (size_t)min(pos + 1, last) * 16);
    uint4 na = epn[0], nb = epn[1];
    unsigned uln = *(const unsigned*)(xlh + (size_t)sd1.x * F1 + j);
    unsigned urn = (sd1.y != sdc.y) ? *(const unsigned*)(xrh + (size_t)sd1.y * F1 + j)
                                    : ur;
    // compute current logit (16 fdot2)
    half2_t e2[8];
    e2[0] = u2h2(ca.x); e2[1] = u2h2(ca.y); e2[2] = u2h2(ca.z); e2[3] = u2h2(ca.w);
    e2[4] = u2h2(cb.x); e2[5] = u2h2(cb.y); e2[6] = u2h2(cb.z); e2[7] = u2h2(cb.w);
    float ea0 = 0.f, ea1 = 0.f;
#pragma unroll
    for (int k = 0; k < 8; ++k) {
      ea0 = FDOT2(e2[k], w0p[k], ea0);
      ea1 = FDOT2(e2[k], w1p[k], ea1);
    }
    half2_t ul2 = u2h2(ul), ur2 = u2h2(ur);
    float m0 = (float)ul2.x + (float)ur2.x + ea0;
    float m1 = (float)ul2.y + (float)ur2.y + ea1;
    m0 = fmaxf(m0, NEG * m0);
    m1 = fmaxf(m1, NEG * m1);
    float p = a0 * m0 + a1 * m1;
#pragma unroll
    for (int m = 8; m >= 1; m >>= 1) p += __shfl_xor(p, m);
    float pe = __expf(p);
    // flush-on-dst-change (wave-uniform branch), then accumulate
    if (sdc.y != cur) {
      atomicAdd(&h1num[(size_t)cur * F1 + j], num0);
      atomicAdd(&h1num[(size_t)cur * F1 + j + 1], num1);
      if (q == 0) atomicAdd(&h1den[cur * 4 + h], den);
      num0 = 0.f; num1 = 0.f; den = 0.f;
      cur = sdc.y;
    }
    num0 += pe * (float)ul2.x;
    num1 += pe * (float)ul2.y;
    den  += pe;
    // rotate
    sdc = sd1; sd1 = sd2; ca = na; cb = nb; ul = uln; ur = urn;
  }
  atomicAdd(&h1num[(size_t)cur * F1 + j], num0);
  atomicAdd(&h1num[(size_t)cur * F1 + j + 1], num1);
  if (q == 0) atomicAdd(&h1den[cur * 4 + h], den);
}

// finish layer 1: h1 = ELU(num/den + bias) -> packed f16 pairs
__global__ __launch_bounds__(256) void k_gatfin1(const float* __restrict__ h1num,
                                                 const float* __restrict__ h1den,
                                                 const float* __restrict__ bias1,
                                                 unsigned* __restrict__ h1h) {
  int tid = blockIdx.x * 256 + threadIdx.x;
  if (tid >= NN * 64) return;
  int n = tid >> 6, lane = tid & 63;
  float2 nm = *(const float2*)(h1num + (size_t)n * F1 + 2 * lane);
  float den = h1den[n * 4 + (lane >> 4)];
  float2 bs = *(const float2*)(bias1 + 2 * lane);
  float o0 = nm.x / den + bs.x;
  float o1 = nm.y / den + bs.y;
  o0 = o0 > 0.f ? o0 : (__expf(o0) - 1.f);   // ELU
  o1 = o1 > 0.f ? o1 : (__expf(o1) - 1.f);
  h1h[tid] = pack2(o0, o1);
}

// xform2: thread = (node, 4-output group of 8); fdot2 on packed pairs.
__global__ __launch_bounds__(256) void k_xform2(const unsigned* __restrict__ h1h,
                                                const unsigned* __restrict__ W2lp,
                                                const unsigned* __restrict__ W2rp,
                                                const float* __restrict__ b2l,
                                                const float* __restrict__ b2r,
                                                ushort_t* __restrict__ xl2h,
                                                ushort_t* __restrict__ xr2h) {
  int tid = blockIdx.x * 256 + threadIdx.x;
  if (tid >= NN * 8) return;
  int n = tid >> 3, g = tid & 7;
  float4 bl = *(const float4*)(b2l + 4 * g);
  float4 br = *(const float4*)(b2r + 4 * g);
  float al0 = bl.x, al1 = bl.y, al2 = bl.z, al3 = bl.w;
  float ar0 = br.x, ar1 = br.y, ar2 = br.z, ar3 = br.w;
  const uint4* hp = (const uint4*)(h1h + (size_t)n * 64);
  const uint4* wl = (const uint4*)W2lp;
  const uint4* wr = (const uint4*)W2rp;
#pragma unroll 4
  for (int kq = 0; kq < 16; ++kq) {
    uint4 hq = hp[kq];
    unsigned hs[4] = {hq.x, hq.y, hq.z, hq.w};
#pragma unroll
    for (int i = 0; i < 4; ++i) {
      int kp = 4 * kq + i;
      uint4 a = wl[kp * 8 + g];
      uint4 b = wr[kp * 8 + g];
      half2_t hv = u2h2(hs[i]);
      al0 = FDOT2(hv, u2h2(a.x), al0);
      al1 = FDOT2(hv, u2h2(a.y), al1);
      al2 = FDOT2(hv, u2h2(a.z), al2);
      al3 = FDOT2(hv, u2h2(a.w), al3);
      ar0 = FDOT2(hv, u2h2(b.x), ar0);
      ar1 = FDOT2(hv, u2h2(b.y), ar1);
      ar2 = FDOT2(hv, u2h2(b.z), ar2);
      ar3 = FDOT2(hv, u2h2(b.w), ar3);
    }
  }
  uint2 ol, orr;
  ol.x = pack2(al0, al1); ol.y = pack2(al2, al3);
  orr.x = pack2(ar0, ar1); orr.y = pack2(ar2, ar3);
  *(uint2*)(xl2h + (size_t)n * F2 + 4 * g) = ol;
  *(uint2*)(xr2h + (size_t)n * F2 + 4 * g) = orr;
}

// FUSED layer-2 GAT: 16-lane group per contiguous sub-chunk; register
// accumulation with flush-on-dst-change atomics (R10 form: conditional gather).
__global__ __launch_bounds__(256, 4) void k_gat2(const ushort_t* __restrict__ eperm,
                                                 const int2* __restrict__ esd,
                                                 const ushort_t* __restrict__ xl2h,
                                                 const ushort_t* __restrict__ xr2h,
                                                 const float* __restrict__ W2e,
                                                 const float* __restrict__ att2,
                                                 float* __restrict__ h2num,
                                                 float* __restrict__ h2den) {
  int lane = threadIdx.x & 63;
  int g = lane >> 4, q = lane & 15, j = 2 * q;
  half2_t w0p[8], w1p[8];
#pragma unroll
  for (int k = 0; k < 8; ++k) {
    w0p[k] = mkh2(W2e[(2 * k) * F2 + j],     W2e[(2 * k + 1) * F2 + j]);
    w1p[k] = mkh2(W2e[(2 * k) * F2 + j + 1], W2e[(2 * k + 1) * F2 + j + 1]);
  }
  float a0 = att2[j], a1 = att2[j + 1];
  int nw  = (gridDim.x * 256) >> 6;
  int wid = (blockIdx.x * 256 + threadIdx.x) >> 6;
  int ngroups = nw * 4;
  int gid = wid * 4 + g;
  int C = (EE2 + ngroups - 1) / ngroups;
  int start = gid * C;
  if (start >= EE2) return;
  int end = min(start + C, EE2);
  const int last = EE2 - 1;

  int2 sdc = esd[start];
  int2 sd1 = esd[min(start + 1, last)];
  const uint4* ep0 = (const uint4*)(eperm + (size_t)start * 16);
  uint4 ca = ep0[0], cb = ep0[1];
  unsigned ul = *(const unsigned*)(xl2h + (size_t)sdc.x * F2 + j);
  unsigned ur = *(const unsigned*)(xr2h + (size_t)sdc.y * F2 + j);

  int cur = sdc.y;
  float num0 = 0.f, num1 = 0.f, den = 0.f;

  for (int pos = start; pos < end; ++pos) {
    int2 sd2 = esd[min(pos + 2, last)];
    const uint4* epn = (const uint4*)(eperm + (size_t)min(pos + 1, last) * 16);
    uint4 na = epn[0], nb = epn[1];
    unsigned uln = *(const unsigned*)(xl2h + (size_t)sd1.x * F2 + j);
    unsigned urn = (sd1.y != sdc.y) ? *(const unsigned*)(xr2h + (size_t)sd1.y * F2 + j)
                                    : ur;
    half2_t e2[8];
    e2[0] = u2h2(ca.x); e2[1] = u2h2(ca.y); e2[2] = u2h2(ca.z); e2[3] = u2h2(ca.w);
    e2[4] = u2h2(cb.x); e2[5] = u2h2(cb.y); e2[6] = u2h2(cb.z); e2[7] = u2h2(cb.w);
    float ea = 0.f, eb = 0.f;
#pragma unroll
    for (int k = 0; k < 8; ++k) {
      ea = FDOT2(e2[k], w0p[k], ea);
      eb = FDOT2(e2[k], w1p[k], eb);
    }
    half2_t ul2 = u2h2(ul), ur2 = u2h2(ur);
    float m0 = (float)ul2.x + (float)ur2.x + ea;
    float m1 = (float)ul2.y + (float)ur2.y + eb;
    m0 = fmaxf(m0, NEG * m0);
    m1 = fmaxf(m1, NEG * m1);
    float p = a0 * m0 + a1 * m1;
#pragma unroll
    for (int m = 8; m >= 1; m >>= 1) p += __shfl_xor(p, m);
    float pe = __expf(p);
    if (sdc.y != cur) {
      atomicAdd(&h2num[(size_t)cur * F2 + j], num0);
      atomicAdd(&h2num[(size_t)cur * F2 + j + 1], num1);
      if (q == 0) atomicAdd(&h2den[cur], den);
      num0 = 0.f; num1 = 0.f; den = 0.f;
      cur = sdc.y;
    }
    num0 += pe * (float)ul2.x;
    num1 += pe * (float)ul2.y;
    den  += pe;
    sdc = sd1; sd1 = sd2; ca = na; cb = nb; ul = uln; ur = urn;
  }
  atomicAdd(&h2num[(size_t)cur * F2 + j], num0);
  atomicAdd(&h2num[(size_t)cur * F2 + j + 1], num1);
  if (q == 0) atomicAdd(&h2den[cur], den);
}

// FUSED finish layer 2 + classifier node-halves: h2 in registers ->
// us = Wc1[0:32]^T h2, ud = Wc1[32:64]^T h2 via 16-lane shfl broadcast.
__global__ __launch_bounds__(256) void k_fin2(const float* __restrict__ h2num,
                                              const float* __restrict__ h2den,
                                              const float* __restrict__ bias2,
                                              const float* __restrict__ Wc1,
                                              float* __restrict__ us,
                                              float* __restrict__ ud) {
  int tid = blockIdx.x * 256 + threadIdx.x;
  if (tid >= NN * 16) return;
  int n = tid >> 4, q = threadIdx.x & 15;
  int lanebase = threadIdx.x & ~15;
  float2 nm = *(const float2*)(h2num + (size_t)n * F2 + 2 * q);
  float den = h2den[n];
  float2 bs = *(const float2*)(bias2 + 2 * q);
  float o0 = nm.x / den + bs.x;
  float o1 = nm.y / den + bs.y;
  o0 = o0 > 0.f ? o0 : (__expf(o0) - 1.f);   // ELU
  o1 = o1 > 0.f ? o1 : (__expf(o1) - 1.f);
  int c0i = 2 * q, c1i = 2 * q + 1;
  float us0 = 0.f, us1 = 0.f, ud0 = 0.f, ud1 = 0.f;
#pragma unroll
  for (int kq = 0; kq < 16; ++kq) {
    float h0 = __shfl(o0, lanebase + kq);
    float h1 = __shfl(o1, lanebase + kq);
    int k0 = 2 * kq, k1 = 2 * kq + 1;
    us0 += h0 * Wc1[k0 * F2 + c0i] + h1 * Wc1[k1 * F2 + c0i];
    us1 += h0 * Wc1[k0 * F2 + c1i] + h1 * Wc1[k1 * F2 + c1i];
    ud0 += h0 * Wc1[(32 + k0) * F2 + c0i] + h1 * Wc1[(32 + k1) * F2 + c0i];
    ud1 += h0 * Wc1[(32 + k0) * F2 + c1i] + h1 * Wc1[(32 + k1) * F2 + c1i];
  }
  *(float2*)(us + (size_t)n * F2 + 2 * q) = make_float2(us0, us1);
  *(float2*)(ud + (size_t)n * F2 + 2 * q) = make_float2(ud0, ud1);
}

// classifier: contiguous 4-edge groups per wave, 2-deep pipeline (edge order).
__global__ __launch_bounds__(256, 4) void k_cls(const int* __restrict__ ei,
                                                const float* __restrict__ edge_attr,
                                                const float* __restrict__ us,
                                                const float* __restrict__ ud,
                                                const float* __restrict__ Wc1,
                                                const float* __restrict__ bc1,
                                                const float* __restrict__ Wc2,
                                                const float* __restrict__ bc2,
                                                float* __restrict__ out) {
  int lane = threadIdx.x & 63;
  int g = lane >> 4, q = lane & 15, j = 2 * q;
  float wk0[16], wk1[16];
#pragma unroll
  for (int k = 0; k < 16; ++k) {
    wk0[k] = Wc1[(64 + k) * F2 + j];
    wk1[k] = Wc1[(64 + k) * F2 + j + 1];
  }
  float b0 = bc1[j], b1 = bc1[j + 1], c0 = Wc2[j], c1 = Wc2[j + 1];
  float bb = bc2[0];
  int nw  = (gridDim.x * 256) >> 6;
  int wid = __builtin_amdgcn_readfirstlane((blockIdx.x * 256 + threadIdx.x) >> 6);
  int C = (((EE + nw - 1) / nw) + 3) & ~3;
  int start = wid * C;
  if (start >= EE) return;
  int end = min(start + C, EE);
  const int last = EE - 1;

  int e0c = min(start + g, last);
  int sn0 = ei[e0c], dn0 = ei[EE + e0c];
  int e1c = min(start + 4 + g, last);
  int sn1 = ei[e1c], dn1 = ei[EE + e1c];
  const float4* ep0 = (const float4*)(edge_attr + (size_t)e0c * 16);
  float4 ca0 = ep0[0], ca1 = ep0[1], ca2 = ep0[2], ca3 = ep0[3];
  float2 su = *(const float2*)(us + (size_t)sn0 * F2 + j);
  float2 du = *(const float2*)(ud + (size_t)dn0 * F2 + j);

  for (int base = start; base < end; base += 4) {
    int e2c = min(base + 8 + g, last);
    int sn2 = ei[e2c], dn2 = ei[EE + e2c];
    const float4* epn = (const float4*)(edge_attr + (size_t)min(base + 4 + g, last) * 16);
    float4 na0 = epn[0], na1 = epn[1], na2 = epn[2], na3 = epn[3];
    float2 sun = *(const float2*)(us + (size_t)sn1 * F2 + j);
    float2 dun = *(const float2*)(ud + (size_t)dn1 * F2 + j);
    float ev[16] = {ca0.x, ca0.y, ca0.z, ca0.w, ca1.x, ca1.y, ca1.z, ca1.w,
                    ca2.x, ca2.y, ca2.z, ca2.w, ca3.x, ca3.y, ca3.z, ca3.w};
    float acc0 = b0 + su.x + du.x;
    float acc1 = b1 + su.y + du.y;
#pragma unroll
    for (int k = 0; k < 16; ++k) { acc0 += ev[k] * wk0[k]; acc1 += ev[k] * wk1[k]; }
    float r = fmaxf(acc0, 0.f) * c0 + fmaxf(acc1, 0.f) * c1;
#pragma unroll
    for (int m = 8; m >= 1; m >>= 1) r += __shfl_xor(r, m);
    int e = base + g;
    if (q == 0 && e < end) out[e] = r + bb;
    sn1 = sn2; dn1 = dn2;
    ca0 = na0; ca1 = na1; ca2 = na2; ca3 = na3;
    su = sun; du = dun;
  }
}

}  // namespace

extern "C" void kernel_launch(void* const* d_in, const int* in_sizes, int n_in,
                              void* d_out, int out_size, void* d_ws, size_t ws_size,
                              hipStream_t stream) {
  const float* x         = (const float*)d_in[0];
  const int*   ei        = (const int*)d_in[1];
  const float* edge_attr = (const float*)d_in[2];
  const float* W1l  = (const float*)d_in[3];
  const float* b1l  = (const float*)d_in[4];
  const float* W1r  = (const float*)d_in[5];
  const float* b1r  = (const float*)d_in[6];
  const float* W1e  = (const float*)d_in[7];
  const float* att1 = (const float*)d_in[8];
  const float* bias1= (const float*)d_in[9];
  const float* W2l  = (const float*)d_in[10];
  const float* b2l  = (const float*)d_in[11];
  const float* W2r  = (const float*)d_in[12];
  const float* b2r  = (const float*)d_in[13];
  const float* W2e  = (const float*)d_in[14];
  const float* att2 = (const float*)d_in[15];
  const float* bias2= (const float*)d_in[16];
  const float* Wc1  = (const float*)d_in[17];
  const float* bc1  = (const float*)d_in[18];
  const float* Wc2  = (const float*)d_in[19];
  const float* bc2  = (const float*)d_in[20];
  float* out = (float*)d_out;

  // ---- workspace layout (4-byte words) ----
  int*  deg      = (int*)d_ws;                            // NN
  int*  cursor   = deg + NN;                              // NN
  int*  loopos   = cursor + NN;                           // NN
  int*  rowstart = loopos + NN;                           // 50008
  int2* esd      = (int2*)(rowstart + 50008);             // EE2 int2
  ushort_t* eperm = (ushort_t*)(esd + EE2);               // EE2*16 f16
  ushort_t* xlh  = eperm + (size_t)EE2 * 16;              // NN*128 f16
  ushort_t* xrh  = xlh + (size_t)NN * F1;                 // NN*128 f16
  float* h1num   = (float*)(xrh + (size_t)NN * F1);       // NN*128 f32
  float* h1den   = h1num + (size_t)NN * F1;               // NN*4
  unsigned* h1h  = (unsigned*)(h1den + (size_t)NN * 4);   // NN*64 u32
  unsigned* W1lp = h1h + (size_t)NN * 64;                 // 4096
  unsigned* W1rp = W1lp + 4096;                           // 4096
  unsigned* W2lp = W1rp + 4096;                           // 2048
  unsigned* W2rp = W2lp + 2048;                           // 2048
  float* us      = (float*)(W2rp + 2048);                 // NN*32
  float* ud      = us + (size_t)NN * F2;                  // NN*32
  unsigned* xh   = (unsigned*)h1num;                      // NN*32 (dead before h1num memset)
  // layer-2 overlays:
  ushort_t* xl2h = xlh;                                   // NN*32 f16
  ushort_t* xr2h = xl2h + (size_t)NN * F2;                // NN*32 f16
  float* h2num   = h1num;                                 // NN*32 f32 (h1num dead after gatfin1)
  float* h2den   = h1num + (size_t)NN * F2;               // NN

  hipMemsetAsync(deg, 0, 2 * (size_t)NN * sizeof(int), stream);  // deg + cursor

  k_prep<<<(NN * 32 + 255) / 256, 256, 0, stream>>>(ei, deg, x, xh,
                                                    W1l, W1r, W2l, W2r,
                                                    W1lp, W1rp, W2lp, W2rp);
  k_scan<<<1, 1024, 0, stream>>>(deg, rowstart);
  k_fill<<<(EE2 + 255) / 256, 256, 0, stream>>>(ei, edge_attr, rowstart, cursor,
                                                esd, eperm, loopos);
  k_loopattr<<<(NN * 16 + 255) / 256, 256, 0, stream>>>(rowstart, loopos, eperm);
  k_xform1<<<(NN * 32 + 255) / 256, 256, 0, stream>>>(xh, W1lp, W1rp, b1l, b1r, xlh, xrh);
  // zero layer-1 accumulators (after xform1: xh overlay is dead now)
  hipMemsetAsync(h1num, 0, (size_t)NN * 132 * sizeof(float), stream);
  k_gat1<<<4096, 256, 0, stream>>>(eperm, esd, xlh, xrh, W1e, att1, h1num, h1den);
  k_gatfin1<<<(NN * 64 + 255) / 256, 256, 0, stream>>>(h1num, h1den, bias1, h1h);
  k_xform2<<<(NN * 8 + 255) / 256, 256, 0, stream>>>(h1h, W2lp, W2rp, b2l, b2r, xl2h, xr2h);
  // zero layer-2 accumulators (h1num region dead after gatfin1)
  hipMemsetAsync(h2num, 0, (size_t)NN * 33 * sizeof(float), stream);
  k_gat2<<<2048, 256, 0, stream>>>(eperm, esd, xl2h, xr2h, W2e, att2, h2num, h2den);
  k_fin2<<<(NN * 16 + 255) / 256, 256, 0, stream>>>(h2num, h2den, bias2, Wc1, us, ud);
  k_cls<<<2048, 256, 0, stream>>>(ei, edge_attr, us, ud, Wc1, bc1, Wc2, bc2, out);
}

// Round 16
// 561.806 us; speedup vs baseline: 1.0243x; 1.0021x over previous
//
#include <hip/hip_runtime.h>

namespace {

constexpr int NN  = 50000;
constexpr int EE  = 1000000;
constexpr int EE2 = EE + NN;          // edges + self loops
constexpr int ND  = 64;               // node_dim
constexpr int F1  = 128;              // 4 heads * 32
constexpr int F2  = 32;               // hidden
constexpr float NEG = 0.2f;

typedef unsigned short ushort_t;
typedef _Float16 half_t;
typedef _Float16 half2_t __attribute__((ext_vector_type(2)));

__device__ __forceinline__ unsigned short f2h(float f) {
  union { half_t h; unsigned short u; } c; c.h = (half_t)f; return c.u;
}
__device__ __forceinline__ float h2f(unsigned short v) {
  union { unsigned short u; half_t h; } c; c.u = v; return (float)c.h;
}
__device__ __forceinline__ half2_t u2h2(unsigned u) {
  union { unsigned u; half2_t h; } c; c.u = u; return c.h;
}
__device__ __forceinline__ unsigned pack2(float x, float y) {
  return (unsigned)f2h(x) | ((unsigned)f2h(y) << 16);
}
__device__ __forceinline__ half2_t mkh2(float x, float y) {
  half2_t r; r.x = (half_t)x; r.y = (half_t)y; return r;
}

#if __has_builtin(__builtin_amdgcn_fdot2)
#define FDOT2(a, b, c) __builtin_amdgcn_fdot2((a), (b), (c), false)
#else
#define FDOT2(a, b, c) ((float)(a).x * (float)(b).x + (float)(a).y * (float)(b).y + (c))
#endif

// FUSED prep: deg atomics + x f16-pack + weight f16-packs (all independent).
__global__ __launch_bounds__(256) void k_prep(const int* __restrict__ ei,
                                              int* __restrict__ deg,
                                              const float* __restrict__ x,
                                              unsigned* __restrict__ xh,
                                              const float* __restrict__ W1l,
                                              const float* __restrict__ W1r,
                                              const float* __restrict__ W2l,
                                              const float* __restrict__ W2r,
                                              unsigned* __restrict__ W1lp,
                                              unsigned* __restrict__ W1rp,
                                              unsigned* __restrict__ W2lp,
                                              unsigned* __restrict__ W2rp) {
  int tid = blockIdx.x * 256 + threadIdx.x;
  if (tid < EE) atomicAdd(&deg[ei[EE + tid]], 1);
  if (tid < NN * 32) {
    float2 v = ((const float2*)x)[tid];
    xh[tid] = pack2(v.x, v.y);
  }
  if (tid < 32 * 128) {
    int kp = tid >> 7, j = tid & 127;
    W1lp[tid] = pack2(W1l[(2 * kp) * F1 + j], W1l[(2 * kp + 1) * F1 + j]);
    W1rp[tid] = pack2(W1r[(2 * kp) * F1 + j], W1r[(2 * kp + 1) * F1 + j]);
  }
  if (tid < 64 * 32) {
    int kp = tid >> 5, c = tid & 31;
    W2lp[tid] = pack2(W2l[(2 * kp) * F2 + c], W2l[(2 * kp + 1) * F2 + c]);
    W2rp[tid] = pack2(W2r[(2 * kp) * F2 + c], W2r[(2 * kp + 1) * F2 + c]);
  }
}

// single block: each thread owns 49 contiguous nodes; block-scan of 1024 partials.
__global__ __launch_bounds__(1024) void k_scan(const int* __restrict__ deg,
                                               int* __restrict__ rowstart) {
  __shared__ int sh[1024];
  int t = threadIdx.x;
  int base = t * 49;
  int end = base + 49; if (end > NN) end = NN;
  int s = 0;
  for (int i = base; i < end; ++i) s += deg[i] + 1;
  sh[t] = s;
  __syncthreads();
  for (int off = 1; off < 1024; off <<= 1) {
    int v = (t >= off) ? sh[t - off] : 0;
    __syncthreads();
    sh[t] += v;
    __syncthreads();
  }
  int run = (t == 0) ? 0 : sh[t - 1];
  for (int i = base; i < end; ++i) { rowstart[i] = run; run += deg[i] + 1; }
  if (t == 1023) rowstart[NN] = sh[1023];
}

// CSR fill: esd (src,dst), f16-permuted edge_attr (eperm), self-loop slot per node.
__global__ __launch_bounds__(256) void k_fill(const int* __restrict__ ei,
                                              const float* __restrict__ edge_attr,
                                              const int* __restrict__ rowstart,
                                              int* __restrict__ cursor,
                                              int2* __restrict__ esd,
                                              ushort_t* __restrict__ eperm,
                                              int* __restrict__ loopos) {
  int i = blockIdx.x * 256 + threadIdx.x;
  if (i >= EE2) return;
  int sn, d;
  if (i < EE) { sn = ei[i]; d = ei[EE + i]; }
  else        { sn = i - EE; d = sn; }
  int pos = rowstart[d] + atomicAdd(&cursor[d], 1);
  esd[pos] = make_int2(sn, d);
  if (i < EE) {
    const float4* s4 = (const float4*)(edge_attr + (size_t)i * 16);
    float4 a = s4[0], b = s4[1], c = s4[2], e = s4[3];
    uint4 lo, hi;
    lo.x = pack2(a.x, a.y); lo.y = pack2(a.z, a.w);
    lo.z = pack2(b.x, b.y); lo.w = pack2(b.z, b.w);
    hi.x = pack2(c.x, c.y); hi.y = pack2(c.z, c.w);
    hi.z = pack2(e.x, e.y); hi.w = pack2(e.z, e.w);
    uint4* t4 = (uint4*)(eperm + (size_t)pos * 16);
    t4[0] = lo; t4[1] = hi;
  } else {
    loopos[d] = pos;
  }
}

// mean of incoming edge attrs -> written into eperm at the self-loop slot (f16).
__global__ __launch_bounds__(256) void k_loopattr(const int* __restrict__ rowstart,
                                                  const int* __restrict__ loopos,
                                                  ushort_t* __restrict__ eperm) {
  int tid = blockIdx.x * 256 + threadIdx.x;
  if (tid >= NN * 16) return;
  int n = tid >> 4, k = tid & 15;
  int s = rowstart[n], t = rowstart[n + 1];
  int lp = loopos[n];
  float acc = 0.f;
  for (int i = s; i < t; ++i) {
    if (i != lp) acc += h2f(eperm[(size_t)i * 16 + k]);
  }
  float dg = (float)(t - s - 1);
  eperm[(size_t)lp * 16 + k] = f2h(acc / fmaxf(dg, 1.f));
}

// xform1: thread = (node, 4-output group); fdot2, coalesced uint4 W loads.
__global__ __launch_bounds__(256) void k_xform1(const unsigned* __restrict__ xh,
                                                const unsigned* __restrict__ W1lp,
                                                const unsigned* __restrict__ W1rp,
                                                const float* __restrict__ b1l,
                                                const float* __restrict__ b1r,
                                                ushort_t* __restrict__ xlh,
                                                ushort_t* __restrict__ xrh) {
  int tid = blockIdx.x * 256 + threadIdx.x;
  if (tid >= NN * 32) return;
  int n = tid >> 5, g = tid & 31;
  float4 bl = *(const float4*)(b1l + 4 * g);
  float4 br = *(const float4*)(b1r + 4 * g);
  float al0 = bl.x, al1 = bl.y, al2 = bl.z, al3 = bl.w;
  float ar0 = br.x, ar1 = br.y, ar2 = br.z, ar3 = br.w;
  const uint4* xp = (const uint4*)(xh + (size_t)n * 32);
  const uint4* wl = (const uint4*)W1lp;
  const uint4* wr = (const uint4*)W1rp;
#pragma unroll
  for (int kq = 0; kq < 8; ++kq) {
    uint4 xq = xp[kq];
    unsigned xs[4] = {xq.x, xq.y, xq.z, xq.w};
#pragma unroll
    for (int i = 0; i < 4; ++i) {
      int kp = 4 * kq + i;
      uint4 a = wl[kp * 32 + g];
      uint4 b = wr[kp * 32 + g];
      half2_t xv = u2h2(xs[i]);
      al0 = FDOT2(xv, u2h2(a.x), al0);
      al1 = FDOT2(xv, u2h2(a.y), al1);
      al2 = FDOT2(xv, u2h2(a.z), al2);
      al3 = FDOT2(xv, u2h2(a.w), al3);
      ar0 = FDOT2(xv, u2h2(b.x), ar0);
      ar1 = FDOT2(xv, u2h2(b.y), ar1);
      ar2 = FDOT2(xv, u2h2(b.z), ar2);
      ar3 = FDOT2(xv, u2h2(b.w), ar3);
    }
  }
  uint2 ol, orr;
  ol.x = pack2(al0, al1); ol.y = pack2(al2, al3);
  orr.x = pack2(ar0, ar1); orr.y = pack2(ar2, ar3);
  *(uint2*)(xlh + (size_t)n * F1 + 4 * g) = ol;
  *(uint2*)(xrh + (size_t)n * F1 + 4 * g) = orr;
}

// FUSED layer-1 GAT: logits + exp + per-dst-run register accumulation,
// flush via fp32 atomics on dst change. Wave per contiguous CSR chunk.
// unroll-2 so the compiler renames pipeline registers (no rotate movs).
__global__ __launch_bounds__(256, 4) void k_gat1(const ushort_t* __restrict__ eperm,
                                                 const int2* __restrict__ esd,
                                                 const ushort_t* __restrict__ xlh,
                                                 const ushort_t* __restrict__ xrh,
                                                 const float* __restrict__ W1e,
                                                 const float* __restrict__ att1,
                                                 float* __restrict__ h1num,
                                                 float* __restrict__ h1den) {
  int lane = threadIdx.x & 63;
  int h = lane >> 4, q = lane & 15, j = h * 32 + 2 * q;
  half2_t w0p[8], w1p[8];
#pragma unroll
  for (int k = 0; k < 8; ++k) {
    w0p[k] = mkh2(W1e[(2 * k) * F1 + j],     W1e[(2 * k + 1) * F1 + j]);
    w1p[k] = mkh2(W1e[(2 * k) * F1 + j + 1], W1e[(2 * k + 1) * F1 + j + 1]);
  }
  float a0 = att1[j], a1 = att1[j + 1];
  int nw  = (gridDim.x * 256) >> 6;
  int wid = __builtin_amdgcn_readfirstlane((blockIdx.x * 256 + threadIdx.x) >> 6);
  int C = (EE2 + nw - 1) / nw;
  int start = wid * C;
  if (start >= EE2) return;
  int end = min(start + C, EE2);
  const int last = EE2 - 1;

  int2 sdc = esd[start];
  int2 sd1 = esd[min(start + 1, last)];
  const uint4* ep0 = (const uint4*)(eperm + (size_t)start * 16);
  uint4 ca = ep0[0], cb = ep0[1];
  unsigned ul = *(const unsigned*)(xlh + (size_t)sdc.x * F1 + j);
  unsigned ur = *(const unsigned*)(xrh + (size_t)sdc.y * F1 + j);

  int cur = sdc.y;
  float num0 = 0.f, num1 = 0.f, den = 0.f;

#pragma unroll 2
  for (int pos = start; pos < end; ++pos) {
    // prefetch next edge
    int2 sd2 = esd[min(pos + 2, last)];
    const uint4* epn = (const uint4*)(eperm + (size_t)min(pos + 1, last) * 16);
    uint4 na = epn[0], nb = epn[1];
    unsigned uln = *(const unsigned*)(xlh + (size_t)sd1.x * F1 + j);
    unsigned urn = (sd1.y != sdc.y) ? *(const unsigned*)(xrh + (size_t)sd1.y * F1 + j)
                                    : ur;
    // compute current logit (16 fdot2)
    half2_t e2[8];
    e2[0] = u2h2(ca.x); e2[1] = u2h2(ca.y); e2[2] = u2h2(ca.z); e2[3] = u2h2(ca.w);
    e2[4] = u2h2(cb.x); e2[5] = u2h2(cb.y); e2[6] = u2h2(cb.z); e2[7] = u2h2(cb.w);
    float ea0 = 0.f, ea1 = 0.f;
#pragma unroll
    for (int k = 0; k < 8; ++k) {
      ea0 = FDOT2(e2[k], w0p[k], ea0);
      ea1 = FDOT2(e2[k], w1p[k], ea1);
    }
    half2_t ul2 = u2h2(ul), ur2 = u2h2(ur);
    float m0 = (float)ul2.x + (float)ur2.x + ea0;
    float m1 = (float)ul2.y + (float)ur2.y + ea1;
    m0 = fmaxf(m0, NEG * m0);
    m1 = fmaxf(m1, NEG * m1);
    float p = a0 * m0 + a1 * m1;
#pragma unroll
    for (int m = 8; m >= 1; m >>= 1) p += __shfl_xor(p, m);
    float pe = __expf(p);
    // flush-on-dst-change (wave-uniform branch), then accumulate
    if (sdc.y != cur) {
      atomicAdd(&h1num[(size_t)cur * F1 + j], num0);
      atomicAdd(&h1num[(size_t)cur * F1 + j + 1], num1);
      if (q == 0) atomicAdd(&h1den[cur * 4 + h], den);
      num0 = 0.f; num1 = 0.f; den = 0.f;
      cur = sdc.y;
    }
    num0 += pe * (float)ul2.x;
    num1 += pe * (float)ul2.y;
    den  += pe;
    // rotate
    sdc = sd1; sd1 = sd2; ca = na; cb = nb; ul = uln; ur = urn;
  }
  atomicAdd(&h1num[(size_t)cur * F1 + j], num0);
  atomicAdd(&h1num[(size_t)cur * F1 + j + 1], num1);
  if (q == 0) atomicAdd(&h1den[cur * 4 + h], den);
}

// finish layer 1: h1 = ELU(num/den + bias) -> packed f16 pairs
__global__ __launch_bounds__(256) void k_gatfin1(const float* __restrict__ h1num,
                                                 const float* __restrict__ h1den,
                                                 const float* __restrict__ bias1,
                                                 unsigned* __restrict__ h1h) {
  int tid = blockIdx.x * 256 + threadIdx.x;
  if (tid >= NN * 64) return;
  int n = tid >> 6, lane = tid & 63;
  float2 nm = *(const float2*)(h1num + (size_t)n * F1 + 2 * lane);
  float den = h1den[n * 4 + (lane >> 4)];
  float2 bs = *(const float2*)(bias1 + 2 * lane);
  float o0 = nm.x / den + bs.x;
  float o1 = nm.y / den + bs.y;
  o0 = o0 > 0.f ? o0 : (__expf(o0) - 1.f);   // ELU
  o1 = o1 > 0.f ? o1 : (__expf(o1) - 1.f);
  h1h[tid] = pack2(o0, o1);
}

// xform2: thread = (node, 4-output group of 8); fdot2 on packed pairs.
__global__ __launch_bounds__(256) void k_xform2(const unsigned* __restrict__ h1h,
                                                const unsigned* __restrict__ W2lp,
                                                const unsigned* __restrict__ W2rp,
                                                const float* __restrict__ b2l,
                                                const float* __restrict__ b2r,
                                                ushort_t* __restrict__ xl2h,
                                                ushort_t* __restrict__ xr2h) {
  int tid = blockIdx.x * 256 + threadIdx.x;
  if (tid >= NN * 8) return;
  int n = tid >> 3, g = tid & 7;
  float4 bl = *(const float4*)(b2l + 4 * g);
  float4 br = *(const float4*)(b2r + 4 * g);
  float al0 = bl.x, al1 = bl.y, al2 = bl.z, al3 = bl.w;
  float ar0 = br.x, ar1 = br.y, ar2 = br.z, ar3 = br.w;
  const uint4* hp = (const uint4*)(h1h + (size_t)n * 64);
  const uint4* wl = (const uint4*)W2lp;
  const uint4* wr = (const uint4*)W2rp;
#pragma unroll 4
  for (int kq = 0; kq < 16; ++kq) {
    uint4 hq = hp[kq];
    unsigned hs[4] = {hq.x, hq.y, hq.z, hq.w};
#pragma unroll
    for (int i = 0; i < 4; ++i) {
      int kp = 4 * kq + i;
      uint4 a = wl[kp * 8 + g];
      uint4 b = wr[kp * 8 + g];
      half2_t hv = u2h2(hs[i]);
      al0 = FDOT2(hv, u2h2(a.x), al0);
      al1 = FDOT2(hv, u2h2(a.y), al1);
      al2 = FDOT2(hv, u2h2(a.z), al2);
      al3 = FDOT2(hv, u2h2(a.w), al3);
      ar0 = FDOT2(hv, u2h2(b.x), ar0);
      ar1 = FDOT2(hv, u2h2(b.y), ar1);
      ar2 = FDOT2(hv, u2h2(b.z), ar2);
      ar3 = FDOT2(hv, u2h2(b.w), ar3);
    }
  }
  uint2 ol, orr;
  ol.x = pack2(al0, al1); ol.y = pack2(al2, al3);
  orr.x = pack2(ar0, ar1); orr.y = pack2(ar2, ar3);
  *(uint2*)(xl2h + (size_t)n * F2 + 4 * g) = ol;
  *(uint2*)(xr2h + (size_t)n * F2 + 4 * g) = orr;
}

// FUSED layer-2 GAT: 16-lane group per contiguous sub-chunk; register
// accumulation with flush-on-dst-change atomics. unroll-2 renaming.
__global__ __launch_bounds__(256, 4) void k_gat2(const ushort_t* __restrict__ eperm,
                                                 const int2* __restrict__ esd,
                                                 const ushort_t* __restrict__ xl2h,
                                                 const ushort_t* __restrict__ xr2h,
                                                 const float* __restrict__ W2e,
                                                 const float* __restrict__ att2,
                                                 float* __restrict__ h2num,
                                                 float* __restrict__ h2den) {
  int lane = threadIdx.x & 63;
  int g = lane >> 4, q = lane & 15, j = 2 * q;
  half2_t w0p[8], w1p[8];
#pragma unroll
  for (int k = 0; k < 8; ++k) {
    w0p[k] = mkh2(W2e[(2 * k) * F2 + j],     W2e[(2 * k + 1) * F2 + j]);
    w1p[k] = mkh2(W2e[(2 * k) * F2 + j + 1], W2e[(2 * k + 1) * F2 + j + 1]);
  }
  float a0 = att2[j], a1 = att2[j + 1];
  int nw  = (gridDim.x * 256) >> 6;
  int wid = (blockIdx.x * 256 + threadIdx.x) >> 6;
  int ngroups = nw * 4;
  int gid = wid * 4 + g;
  int C = (EE2 + ngroups - 1) / ngroups;
  int start = gid * C;
  if (start >= EE2) return;
  int end = min(start + C, EE2);
  const int last = EE2 - 1;

  int2 sdc = esd[start];
  int2 sd1 = esd[min(start + 1, last)];
  const uint4* ep0 = (const uint4*)(eperm + (size_t)start * 16);
  uint4 ca = ep0[0], cb = ep0[1];
  unsigned ul = *(const unsigned*)(xl2h + (size_t)sdc.x * F2 + j);
  unsigned ur = *(const unsigned*)(xr2h + (size_t)sdc.y * F2 + j);

  int cur = sdc.y;
  float num0 = 0.f, num1 = 0.f, den = 0.f;

#pragma unroll 2
  for (int pos = start; pos < end; ++pos) {
    int2 sd2 = esd[min(pos + 2, last)];
    const uint4* epn = (const uint4*)(eperm + (size_t)min(pos + 1, last) * 16);
    uint4 na = epn[0], nb = epn[1];
    unsigned uln = *(const unsigned*)(xl2h + (size_t)sd1.x * F2 + j);
    unsigned urn = (sd1.y != sdc.y) ? *(const unsigned*)(xr2h + (size_t)sd1.y * F2 + j)
                                    : ur;
    half2_t e2[8];
    e2[0] = u2h2(ca.x); e2[1] = u2h2(ca.y); e2[2] = u2h2(ca.z); e2[3] = u2h2(ca.w);
    e2[4] = u2h2(cb.x); e2[5] = u2h2(cb.y); e2[6] = u2h2(cb.z); e2[7] = u2h2(cb.w);
    float ea = 0.f, eb = 0.f;
#pragma unroll
    for (int k = 0; k < 8; ++k) {
      ea = FDOT2(e2[k], w0p[k], ea);
      eb = FDOT2(e2[k], w1p[k], eb);
    }
    half2_t ul2 = u2h2(ul), ur2 = u2h2(ur);
    float m0 = (float)ul2.x + (float)ur2.x + ea;
    float m1 = (float)ul2.y + (float)ur2.y + eb;
    m0 = fmaxf(m0, NEG * m0);
    m1 = fmaxf(m1, NEG * m1);
    float p = a0 * m0 + a1 * m1;
#pragma unroll
    for (int m = 8; m >= 1; m >>= 1) p += __shfl_xor(p, m);
    float pe = __expf(p);
    if (sdc.y != cur) {
      atomicAdd(&h2num[(size_t)cur * F2 + j], num0);
      atomicAdd(&h2num[(size_t)cur * F2 + j + 1], num1);
      if (q == 0) atomicAdd(&h2den[cur], den);
      num0 = 0.f; num1 = 0.f; den = 0.f;
      cur = sdc.y;
    }
    num0 += pe * (float)ul2.x;
    num1 += pe * (float)ul2.y;
    den  += pe;
    sdc = sd1; sd1 = sd2; ca = na; cb = nb; ul = uln; ur = urn;
  }
  atomicAdd(&h2num[(size_t)cur * F2 + j], num0);
  atomicAdd(&h2num[(size_t)cur * F2 + j + 1], num1);
  if (q == 0) atomicAdd(&h2den[cur], den);
}

// FUSED finish layer 2 + classifier node-halves: h2 in registers ->
// us = Wc1[0:32]^T h2, ud = Wc1[32:64]^T h2 via 16-lane shfl broadcast.
__global__ __launch_bounds__(256) void k_fin2(const float* __restrict__ h2num,
                                              const float* __restrict__ h2den,
                                              const float* __restrict__ bias2,
                                              const float* __restrict__ Wc1,
                                              float* __restrict__ us,
                                              float* __restrict__ ud) {
  int tid = blockIdx.x * 256 + threadIdx.x;
  if (tid >= NN * 16) return;
  int n = tid >> 4, q = threadIdx.x & 15;
  int lanebase = threadIdx.x & ~15;
  float2 nm = *(const float2*)(h2num + (size_t)n * F2 + 2 * q);
  float den = h2den[n];
  float2 bs = *(const float2*)(bias2 + 2 * q);
  float o0 = nm.x / den + bs.x;
  float o1 = nm.y / den + bs.y;
  o0 = o0 > 0.f ? o0 : (__expf(o0) - 1.f);   // ELU
  o1 = o1 > 0.f ? o1 : (__expf(o1) - 1.f);
  int c0i = 2 * q, c1i = 2 * q + 1;
  float us0 = 0.f, us1 = 0.f, ud0 = 0.f, ud1 = 0.f;
#pragma unroll
  for (int kq = 0; kq < 16; ++kq) {
    float h0 = __shfl(o0, lanebase + kq);
    float h1 = __shfl(o1, lanebase + kq);
    int k0 = 2 * kq, k1 = 2 * kq + 1;
    us0 += h0 * Wc1[k0 * F2 + c0i] + h1 * Wc1[k1 * F2 + c0i];
    us1 += h0 * Wc1[k0 * F2 + c1i] + h1 * Wc1[k1 * F2 + c1i];
    ud0 += h0 * Wc1[(32 + k0) * F2 + c0i] + h1 * Wc1[(32 + k1) * F2 + c0i];
    ud1 += h0 * Wc1[(32 + k0) * F2 + c1i] + h1 * Wc1[(32 + k1) * F2 + c1i];
  }
  *(float2*)(us + (size_t)n * F2 + 2 * q) = make_float2(us0, us1);
  *(float2*)(ud + (size_t)n * F2 + 2 * q) = make_float2(ud0, ud1);
}

// classifier: contiguous 4-edge groups per wave, 2-deep pipeline (edge order).
__global__ __launch_bounds__(256, 4) void k_cls(const int* __restrict__ ei,
                                                const float* __restrict__ edge_attr,
                                                const float* __restrict__ us,
                                                const float* __restrict__ ud,
                                                const float* __restrict__ Wc1,
                                                const float* __restrict__ bc1,
                                                const float* __restrict__ Wc2,
                                                const float* __restrict__ bc2,
                                                float* __restrict__ out) {
  int lane = threadIdx.x & 63;
  int g = lane >> 4, q = lane & 15, j = 2 * q;
  float wk0[16], wk1[16];
#pragma unroll
  for (int k = 0; k < 16; ++k) {
    wk0[k] = Wc1[(64 + k) * F2 + j];
    wk1[k] = Wc1[(64 + k) * F2 + j + 1];
  }
  float b0 = bc1[j], b1 = bc1[j + 1], c0 = Wc2[j], c1 = Wc2[j + 1];
  float bb = bc2[0];
  int nw  = (gridDim.x * 256) >> 6;
  int wid = __builtin_amdgcn_readfirstlane((blockIdx.x * 256 + threadIdx.x) >> 6);
  int C = (((EE + nw - 1) / nw) + 3) & ~3;
  int start = wid * C;
  if (start >= EE) return;
  int end = min(start + C, EE);
  const int last = EE - 1;

  int e0c = min(start + g, last);
  int sn0 = ei[e0c], dn0 = ei[EE + e0c];
  int e1c = min(start + 4 + g, last);
  int sn1 = ei[e1c], dn1 = ei[EE + e1c];
  const float4* ep0 = (const float4*)(edge_attr + (size_t)e0c * 16);
  float4 ca0 = ep0[0], ca1 = ep0[1], ca2 = ep0[2], ca3 = ep0[3];
  float2 su = *(const float2*)(us + (size_t)sn0 * F2 + j);
  float2 du = *(const float2*)(ud + (size_t)dn0 * F2 + j);

#pragma unroll 2
  for (int base = start; base < end; base += 4) {
    int e2c = min(base + 8 + g, last);
    int sn2 = ei[e2c], dn2 = ei[EE + e2c];
    const float4* epn = (const float4*)(edge_attr + (size_t)min(base + 4 + g, last) * 16);
    float4 na0 = epn[0], na1 = epn[1], na2 = epn[2], na3 = epn[3];
    float2 sun = *(const float2*)(us + (size_t)sn1 * F2 + j);
    float2 dun = *(const float2*)(ud + (size_t)dn1 * F2 + j);
    float ev[16] = {ca0.x, ca0.y, ca0.z, ca0.w, ca1.x, ca1.y, ca1.z, ca1.w,
                    ca2.x, ca2.y, ca2.z, ca2.w, ca3.x, ca3.y, ca3.z, ca3.w};
    float acc0 = b0 + su.x + du.x;
    float acc1 = b1 + su.y + du.y;
#pragma unroll
    for (int k = 0; k < 16; ++k) { acc0 += ev[k] * wk0[k]; acc1 += ev[k] * wk1[k]; }
    float r = fmaxf(acc0, 0.f) * c0 + fmaxf(acc1, 0.f) * c1;
#pragma unroll
    for (int m = 8; m >= 1; m >>= 1) r += __shfl_xor(r, m);
    int e = base + g;
    if (q == 0 && e < end) out[e] = r + bb;
    sn1 = sn2; dn1 = dn2;
    ca0 = na0; ca1 = na1; ca2 = na2; ca3 = na3;
    su = sun; du = dun;
  }
}

}  // namespace

extern "C" void kernel_launch(void* const* d_in, const int* in_sizes, int n_in,
                              void* d_out, int out_size, void* d_ws, size_t ws_size,
                              hipStream_t stream) {
  const float* x         = (const float*)d_in[0];
  const int*   ei        = (const int*)d_in[1];
  const float* edge_attr = (const float*)d_in[2];
  const float* W1l  = (const float*)d_in[3];
  const float* b1l  = (const float*)d_in[4];
  const float* W1r  = (const float*)d_in[5];
  const float* b1r  = (const float*)d_in[6];
  const float* W1e  = (const float*)d_in[7];
  const float* att1 = (const float*)d_in[8];
  const float* bias1= (const float*)d_in[9];
  const float* W2l  = (const float*)d_in[10];
  const float* b2l  = (const float*)d_in[11];
  const float* W2r  = (const float*)d_in[12];
  const float* b2r  = (const float*)d_in[13];
  const float* W2e  = (const float*)d_in[14];
  const float* att2 = (const float*)d_in[15];
  const float* bias2= (const float*)d_in[16];
  const float* Wc1  = (const float*)d_in[17];
  const float* bc1  = (const float*)d_in[18];
  const float* Wc2  = (const float*)d_in[19];
  const float* bc2  = (const float*)d_in[20];
  float* out = (float*)d_out;

  // ---- workspace layout (4-byte words) ----
  int*  deg      = (int*)d_ws;                            // NN
  int*  cursor   = deg + NN;                              // NN
  int*  loopos   = cursor + NN;                           // NN
  int*  rowstart = loopos + NN;                           // 50008
  int2* esd      = (int2*)(rowstart + 50008);             // EE2 int2
  ushort_t* eperm = (ushort_t*)(esd + EE2);               // EE2*16 f16
  ushort_t* xlh  = eperm + (size_t)EE2 * 16;              // NN*128 f16
  ushort_t* xrh  = xlh + (size_t)NN * F1;                 // NN*128 f16
  float* h1num   = (float*)(xrh + (size_t)NN * F1);       // NN*128 f32
  float* h1den   = h1num + (size_t)NN * F1;               // NN*4
  unsigned* h1h  = (unsigned*)(h1den + (size_t)NN * 4);   // NN*64 u32
  unsigned* W1lp = h1h + (size_t)NN * 64;                 // 4096
  unsigned* W1rp = W1lp + 4096;                           // 4096
  unsigned* W2lp = W1rp + 4096;                           // 2048
  unsigned* W2rp = W2lp + 2048;                           // 2048
  float* us      = (float*)(W2rp + 2048);                 // NN*32
  float* ud      = us + (size_t)NN * F2;                  // NN*32
  unsigned* xh   = (unsigned*)h1num;                      // NN*32 (dead before h1num memset)
  // layer-2 overlays:
  ushort_t* xl2h = xlh;                                   // NN*32 f16
  ushort_t* xr2h = xl2h + (size_t)NN * F2;                // NN*32 f16
  float* h2num   = h1num;                                 // NN*32 f32 (h1num dead after gatfin1)
  float* h2den   = h1num + (size_t)NN * F2;               // NN

  hipMemsetAsync(deg, 0, 2 * (size_t)NN * sizeof(int), stream);  // deg + cursor

  k_prep<<<(NN * 32 + 255) / 256, 256, 0, stream>>>(ei, deg, x, xh,
                                                    W1l, W1r, W2l, W2r,
                                                    W1lp, W1rp, W2lp, W2rp);
  k_scan<<<1, 1024, 0, stream>>>(deg, rowstart);
  k_fill<<<(EE2 + 255) / 256, 256, 0, stream>>>(ei, edge_attr, rowstart, cursor,
                                                esd, eperm, loopos);
  k_loopattr<<<(NN * 16 + 255) / 256, 256, 0, stream>>>(rowstart, loopos, eperm);
  k_xform1<<<(NN * 32 + 255) / 256, 256, 0, stream>>>(xh, W1lp, W1rp, b1l, b1r, xlh, xrh);
  // zero layer-1 accumulators (after xform1: xh overlay is dead now)
  hipMemsetAsync(h1num, 0, (size_t)NN * 132 * sizeof(float), stream);
  k_gat1<<<4096, 256, 0, stream>>>(eperm, esd, xlh, xrh, W1e, att1, h1num, h1den);
  k_gatfin1<<<(NN * 64 + 255) / 256, 256, 0, stream>>>(h1num, h1den, bias1, h1h);
  k_xform2<<<(NN * 8 + 255) / 256, 256, 0, stream>>>(h1h, W2lp, W2rp, b2l, b2r, xl2h, xr2h);
  // zero layer-2 accumulators (h1num region dead after gatfin1)
  hipMemsetAsync(h2num, 0, (size_t)NN * 33 * sizeof(float), stream);
  k_gat2<<<2048, 256, 0, stream>>>(eperm, esd, xl2h, xr2h, W2e, att2, h2num, h2den);
  k_fin2<<<(NN * 16 + 255) / 256, 256, 0, stream>>>(h2num, h2den, bias2, Wc1, us, ud);
  k_cls<<<2048, 256, 0, stream>>>(ei, edge_attr, us, ud, Wc1, bc1, Wc2, bc2, out);
}